// Round 5
// baseline (269.393 us; speedup 1.0000x reference)
//
#include <hip/hip_runtime.h>

#define N_NODES 50000
#define N_EDGES 800000
#define CAP 48
#define PB_BLOCKS 2560
// IN_F = 64, OUT_F = 64, EDGE_F = 16, d_in1 = 144
// NOTE: harness passes ALL integer inputs as int32 — edge_index is int32[2*E],
// src = ei[e], dst = ei[E+e].
// NOTE (round 3): hipLaunchCooperativeKernel inside kernel_launch broke the
// harness (graph capture) — container failed twice. DO NOT use coop launch.

#define FMA16(acc, ep, wreg)                                                 \
    {                                                                        \
        float4 _e0 = (ep)[0], _e1 = (ep)[1], _e2 = (ep)[2], _e3 = (ep)[3];   \
        acc += _e0.x * wreg[0];  acc += _e0.y * wreg[1];                     \
        acc += _e0.z * wreg[2];  acc += _e0.w * wreg[3];                     \
        acc += _e1.x * wreg[4];  acc += _e1.y * wreg[5];                     \
        acc += _e1.z * wreg[6];  acc += _e1.w * wreg[7];                     \
        acc += _e2.x * wreg[8];  acc += _e2.y * wreg[9];                     \
        acc += _e2.z * wreg[10]; acc += _e2.w * wreg[11];                    \
        acc += _e3.x * wreg[12]; acc += _e3.y * wreg[13];                    \
        acc += _e3.z * wreg[14]; acc += _e3.w * wreg[15];                    \
    }

// ---------------------------------------------------------------------------
// prebuild_kernel (uniform): EVERY block does
//   (1) build chunk: grid-stride over edges, bucket e by dst (4-byte slot)
//   (2) pre chunk:   xa = x @ W1[0:64,:], xb = x @ W1[64:128,:]
// Uniform work per block -> build atomics overlap pre latency; pre gets
// 5120 wave-pairs (~10 iters) instead of 1024 (~49) -> latency hidden.
// cnt/ocnt must be zeroed before launch (memsetAsync).
// ---------------------------------------------------------------------------
__global__ __launch_bounds__(256) void prebuild_kernel(
    const float* __restrict__ x, const float* __restrict__ W1,
    float* __restrict__ xa, float* __restrict__ xb,
    const int* __restrict__ ei, unsigned* __restrict__ cnt,
    unsigned* __restrict__ ocnt, unsigned* __restrict__ slot,
    unsigned* __restrict__ oflow)
{
    const int tid = threadIdx.x;

    // ---- build part: bucket edges by dst (store edge id only, 4 B) ----
    for (int e = blockIdx.x * 256 + tid; e < N_EDGES; e += PB_BLOCKS * 256) {
        const int d = ei[N_EDGES + e];
        const unsigned pos = atomicAdd(&cnt[d], 1u);
        if (pos < CAP) {
            slot[(size_t)d * CAP + pos] = (unsigned)e;
        } else {
            const unsigned oi = atomicAdd(ocnt, 1u);
            oflow[oi] = (unsigned)e;
        }
    }

    // ---- pre part: wave per (node-subset, product) ----
    const int w = tid >> 6;
    const int j = tid & 63;
    const int gw = blockIdx.x * 4 + w;
    const int p = gw & 1;              // 0 -> xa, 1 -> xb
    const int pair = gw >> 1;
    const int npair = PB_BLOCKS * 2;   // 5120

    float wc[64];
#pragma unroll
    for (int k = 0; k < 64; ++k) wc[k] = W1[(p * 64 + k) * 64 + j];
    float* __restrict__ outp = p ? xb : xa;
    for (int i = pair; i < N_NODES; i += npair) {
        const float4* xr = (const float4*)&x[(size_t)i * 64];
        float acc = 0.f;
#pragma unroll
        for (int k4 = 0; k4 < 16; ++k4) {
            float4 xv = xr[k4];
            acc += xv.x * wc[k4 * 4 + 0];
            acc += xv.y * wc[k4 * 4 + 1];
            acc += xv.z * wc[k4 * 4 + 2];
            acc += xv.w * wc[k4 * 4 + 3];
        }
        outp[(size_t)i * 64 + j] = acc;
    }
}

// ---------------------------------------------------------------------------
// nodefused_kernel: one wave per dst node.
//   hacc = sum_e relu(xa[src]+xb[n]+ea@W1c+b1)    (aggregation)
//   out[n] = hacc @ W2 + dcap*b2                  (W2 hoisted out of seg-sum)
// slot holds edge ids (4 B); src gathered from ei in one 64-wide gather.
// Chunked depth-16 memory parallelism: per 16-edge chunk, stage the 16 ea
// rows with one b128 load per lane into LDS, issue all 16 xa gathers into
// unrolled registers, then consume via broadcast ds_read_b128 + 16 FMA/edge.
// ---------------------------------------------------------------------------
__global__ __launch_bounds__(256) void nodefused_kernel(
    const float* __restrict__ xa, const float* __restrict__ xb,
    const float* __restrict__ ea, const unsigned* __restrict__ slot,
    const int* __restrict__ ei, const unsigned* __restrict__ cnt,
    const float* __restrict__ W1, const float* __restrict__ b1,
    const float* __restrict__ W2, const float* __restrict__ b2,
    float* __restrict__ out)
{
    __shared__ __align__(16) float sea[4][CAP * 16];   // 12 KB / block

    const int w = threadIdx.x >> 6;
    const int j = threadIdx.x & 63;
    const int n = blockIdx.x * 4 + w;

    float w1c[16];
#pragma unroll
    for (int k = 0; k < 16; ++k) w1c[k] = W1[(128 + k) * 64 + j];
    const float b1j = b1[j];
    const float b2j = b2[j];

    const int deg = (int)cnt[n];
    const int dcap = deg < CAP ? deg : CAP;

    // lane j holds edge id and (gathered) src of slot j
    int ev = 0, sv = 0;
    if (j < dcap) {
        ev = (int)slot[(size_t)n * CAP + j];
        sv = ei[ev];
    }

    const float base = xb[(size_t)n * 64 + j] + b1j;

    float hacc = 0.f;
    if (dcap > 0) {
        const int sub = j >> 2;        // which edge of the chunk this lane stages
        const int q   = j & 3;         // which float4 quarter of that edge

        for (int b0 = 0; b0 < dcap; b0 += 16) {
            // ---- stage ea rows of edges b0..b0+15 into LDS (1 b128/lane) ----
            {
                int ii = b0 + sub;
                const int ic = ii < dcap ? ii : dcap - 1;   // clamp: benign dup
                const unsigned eid = (unsigned)__shfl(ev, ic);
                float4 v = *(const float4*)(ea + (size_t)eid * 16 + q * 4);
                *(float4*)&sea[w][ic * 16 + q * 4] = v;
            }
            // ---- issue 16 xa gathers into registers (static indexing) ----
            float xv[16];
#pragma unroll
            for (int t = 0; t < 16; ++t) {
                int ii = b0 + t;
                const int ic = ii < dcap ? ii : dcap - 1;   // uniform select
                const unsigned ss =
                    (unsigned)__builtin_amdgcn_readlane(sv, ic);
                xv[t] = xa[(size_t)ss * 64 + j];
            }
            // ---- consume 16 edges ----
#pragma unroll
            for (int t = 0; t < 16; ++t) {
                const int ii = b0 + t;
                if (ii < dcap) {                            // uniform branch
                    const float4* ep = (const float4*)&sea[w][ii * 16];
                    float acc = base + xv[t];
                    FMA16(acc, ep, w1c);
                    hacc += fmaxf(acc, 0.f);
                }
            }
        }
    }

    // ---- fused epilogue: out[n] = hacc @ W2 + dcap * b2 ----
    sea[w][j] = hacc;                  // broadcast via LDS (wave-internal)
    float msg = (float)dcap * b2j;
#pragma unroll
    for (int k4 = 0; k4 < 16; ++k4) {
        float4 hv = *(const float4*)&sea[w][k4 * 4];        // uniform broadcast
        msg += hv.x * W2[(k4 * 4 + 0) * 64 + j];
        msg += hv.y * W2[(k4 * 4 + 1) * 64 + j];
        msg += hv.z * W2[(k4 * 4 + 2) * 64 + j];
        msg += hv.w * W2[(k4 * 4 + 3) * 64 + j];
    }
    out[(size_t)n * 64 + j] = msg;
}

// ---------------------------------------------------------------------------
// overflow_kernel: correctness net for pos >= CAP edges (expected 0 edges).
// Runs AFTER nodefused (stream order); adds full W2-transformed message + b2.
// ---------------------------------------------------------------------------
__global__ __launch_bounds__(256) void overflow_kernel(
    const float* __restrict__ xa, const float* __restrict__ xb,
    const int* __restrict__ ei, const float* __restrict__ ea,
    const float* __restrict__ W1, const float* __restrict__ b1,
    const float* __restrict__ W2, const float* __restrict__ b2,
    const unsigned* __restrict__ ocnt, const unsigned* __restrict__ oflow,
    float* __restrict__ out)
{
    const unsigned oc = *ocnt;
    if (oc == 0) return;
    const int w = threadIdx.x >> 6;
    const int j = threadIdx.x & 63;
    unsigned idx = blockIdx.x * 4 + w;
    const unsigned stride = gridDim.x * 4;
    for (; idx < oc; idx += stride) {
        const int e = (int)oflow[idx];
        const int s = ei[e];
        const int dd = ei[N_EDGES + e];
        float acc = xa[(size_t)s * 64 + j] + xb[(size_t)dd * 64 + j] + b1[j];
        for (int k = 0; k < 16; ++k)
            acc += ea[(size_t)e * 16 + k] * W1[(128 + k) * 64 + j];
        const float h = fmaxf(acc, 0.f);
        float msg = b2[j];
        for (int k = 0; k < 64; ++k) msg += __shfl(h, k) * W2[k * 64 + j];
        unsafeAtomicAdd(&out[(size_t)dd * 64 + j], msg);
    }
}

// ---------------------------------------------------------------------------
// OLD PATH kernels (ws too small for bucketed pipeline)
// ---------------------------------------------------------------------------
__global__ __launch_bounds__(256) void pre_kernel(
    const float* __restrict__ x, const float* __restrict__ W1,
    float* __restrict__ xa, float* __restrict__ xb)
{
    const int w = threadIdx.x >> 6;
    const int j = threadIdx.x & 63;
    const int gw = blockIdx.x * 4 + w;
    const int p = gw & 1;
    const int pair = gw >> 1;
    const int npair = (gridDim.x * 4) >> 1;

    float wc[64];
#pragma unroll
    for (int k = 0; k < 64; ++k) wc[k] = W1[(p * 64 + k) * 64 + j];
    float* __restrict__ outp = p ? xb : xa;
    for (int i = pair; i < N_NODES; i += npair) {
        const float4* xr = (const float4*)&x[(size_t)i * 64];
        float acc = 0.f;
#pragma unroll
        for (int k4 = 0; k4 < 16; ++k4) {
            float4 xv = xr[k4];
            acc += xv.x * wc[k4 * 4 + 0];
            acc += xv.y * wc[k4 * 4 + 1];
            acc += xv.z * wc[k4 * 4 + 2];
            acc += xv.w * wc[k4 * 4 + 3];
        }
        outp[(size_t)i * 64 + j] = acc;
    }
}

__global__ __launch_bounds__(256) void edge_kernel(
    const float* __restrict__ xa, const float* __restrict__ xb,
    const int* __restrict__ ei,
    const float* __restrict__ edge_attr,
    const float* __restrict__ W1, const float* __restrict__ b1,
    const float* __restrict__ W2, const float* __restrict__ b2,
    float* __restrict__ out)
{
    __shared__ __align__(16) float eas[4][256];
    __shared__ __align__(16) float hs[4][16][64];

    const int w = threadIdx.x >> 6;
    const int j = threadIdx.x & 63;
    const int wt = blockIdx.x * 4 + w;
    const long eb = (long)wt * 16;

    float w1c[16];
    float w2c[64];
#pragma unroll
    for (int k = 0; k < 16; ++k) w1c[k] = W1[(128 + k) * 64 + j];
#pragma unroll
    for (int k = 0; k < 64; ++k) w2c[k] = W2[k * 64 + j];
    const float b1j = b1[j];
    const float b2j = b2[j];

    int idxv = 0;
    if (j < 16)       idxv = ei[eb + j];
    else if (j < 32)  idxv = ei[(long)N_EDGES + eb + (j - 16)];

    {
        float4 ev = *(const float4*)&edge_attr[eb * 16 + j * 4];
        *(float4*)&eas[w][j * 4] = ev;
    }

#pragma unroll 4
    for (int e = 0; e < 16; ++e) {
        const int s  = __shfl(idxv, e);
        const int dd = __shfl(idxv, 16 + e);

        float acc = xa[(long)s * 64 + j] + xb[(long)dd * 64 + j] + b1j;
#pragma unroll
        for (int k4 = 0; k4 < 4; ++k4) {
            float4 ev = *(const float4*)&eas[w][e * 16 + k4 * 4];
            acc += ev.x * w1c[k4 * 4 + 0];
            acc += ev.y * w1c[k4 * 4 + 1];
            acc += ev.z * w1c[k4 * 4 + 2];
            acc += ev.w * w1c[k4 * 4 + 3];
        }
        const float h = fmaxf(acc, 0.f);
        hs[w][e][j] = h;

        float msg = b2j;
#pragma unroll
        for (int k4 = 0; k4 < 16; ++k4) {
            float4 hv = *(const float4*)&hs[w][e][k4 * 4];
            msg += hv.x * w2c[k4 * 4 + 0];
            msg += hv.y * w2c[k4 * 4 + 1];
            msg += hv.z * w2c[k4 * 4 + 2];
            msg += hv.w * w2c[k4 * 4 + 3];
        }
        unsafeAtomicAdd(&out[(long)dd * 64 + j], msg);
    }
}

__global__ __launch_bounds__(256) void fallback_kernel(
    const float* __restrict__ x, const int* __restrict__ ei,
    const float* __restrict__ edge_attr,
    const float* __restrict__ W1, const float* __restrict__ b1,
    const float* __restrict__ W2, const float* __restrict__ b2,
    float* __restrict__ out)
{
    const int w = threadIdx.x >> 6;
    const int j = threadIdx.x & 63;
    const long e = (long)blockIdx.x * 4 + w;
    if (e >= N_EDGES) return;
    const int s  = ei[e];
    const int dd = ei[(long)N_EDGES + e];

    float acc = b1[j];
    for (int k = 0; k < 64; ++k) acc += x[(long)s  * 64 + k] * W1[k * 64 + j];
    for (int k = 0; k < 64; ++k) acc += x[(long)dd * 64 + k] * W1[(64 + k) * 64 + j];
    for (int k = 0; k < 16; ++k) acc += edge_attr[e * 16 + k] * W1[(128 + k) * 64 + j];
    const float h = fmaxf(acc, 0.f);

    float msg = b2[j];
    for (int k = 0; k < 64; ++k) msg += __shfl(h, k) * W2[k * 64 + j];
    unsafeAtomicAdd(&out[(long)dd * 64 + j], msg);
}

extern "C" void kernel_launch(void* const* d_in, const int* in_sizes, int n_in,
                              void* d_out, int out_size, void* d_ws, size_t ws_size,
                              hipStream_t stream) {
    const float* x   = (const float*)d_in[0];
    const int*   ei  = (const int*)d_in[1];
    const float* ea  = (const float*)d_in[2];
    const float* W1  = (const float*)d_in[3];
    const float* b1  = (const float*)d_in[4];
    const float* W2  = (const float*)d_in[5];
    const float* b2  = (const float*)d_in[6];
    float* out = (float*)d_out;

    const size_t NF = (size_t)N_NODES * 64;
    const size_t need_main = 2 * NF * 4                    // xa, xb
                           + (size_t)N_NODES * 4 + 256     // cnt, ocnt(+pad)
                           + (size_t)N_NODES * CAP * 4     // slot (edge id)
                           + (size_t)N_EDGES * 4;          // oflow
    const size_t need_old = 2 * NF * 4;

    if (ws_size >= need_main) {
        char* p = (char*)d_ws;
        float*    xauf  = (float*)p;    p += NF * 4;
        float*    xbuf  = (float*)p;    p += NF * 4;
        unsigned* cnt   = (unsigned*)p; p += (size_t)N_NODES * 4;
        unsigned* ocnt  = (unsigned*)p; p += 256;
        unsigned* slot  = (unsigned*)p; p += (size_t)N_NODES * CAP * 4;
        unsigned* oflow = (unsigned*)p;

        hipMemsetAsync(cnt, 0, (size_t)N_NODES * 4 + 256, stream);
        prebuild_kernel<<<PB_BLOCKS, 256, 0, stream>>>(
            x, W1, xauf, xbuf, ei, cnt, ocnt, slot, oflow);
        nodefused_kernel<<<N_NODES / 4, 256, 0, stream>>>(
            xauf, xbuf, ea, slot, ei, cnt, W1, b1, W2, b2, out);
        overflow_kernel<<<16, 256, 0, stream>>>(xauf, xbuf, ei, ea, W1, b1,
                                                W2, b2, ocnt, oflow, out);
    } else if (ws_size >= need_old) {
        hipMemsetAsync(out, 0, (size_t)N_NODES * 64 * sizeof(float), stream);
        float* xauf = (float*)d_ws;
        float* xbuf = xauf + NF;
        pre_kernel<<<512, 256, 0, stream>>>(x, W1, xauf, xbuf);
        edge_kernel<<<N_EDGES / 64, 256, 0, stream>>>(xauf, xbuf, ei, ea,
                                                      W1, b1, W2, b2, out);
    } else {
        hipMemsetAsync(out, 0, (size_t)N_NODES * 64 * sizeof(float), stream);
        fallback_kernel<<<N_EDGES / 4, 256, 0, stream>>>(x, ei, ea,
                                                         W1, b1, W2, b2, out);
    }
}